// Round 5
// baseline (302.086 us; speedup 1.0000x reference)
//
#include <hip/hip_runtime.h>

#define B_ 64
#define C_ 128
#define T_ 128
#define J_ 25
#define PIT 136   // k_attn LDS pitch (ushorts)
#define XP 40     // F j-pitch (ushorts)
#define GP 136    // G^T c-pitch (ushorts)
#define TT 4      // t's per k_main block

typedef unsigned short ushort_t;
typedef __attribute__((ext_vector_type(8))) unsigned short ushort8;
typedef __attribute__((ext_vector_type(4))) unsigned short ushort4_t;
typedef __attribute__((ext_vector_type(8))) _Float16 half8;
typedef __attribute__((ext_vector_type(4))) float f32x4;
typedef float f32x4u __attribute__((ext_vector_type(4), aligned(4)));
typedef unsigned short ushort8u __attribute__((ext_vector_type(8), aligned(2)));

__device__ __forceinline__ float bf2f(ushort_t u) {
  unsigned int v = ((unsigned int)u) << 16;
  return __builtin_bit_cast(float, v);
}
__device__ __forceinline__ ushort_t f2bf(float f) {
  unsigned int u = __builtin_bit_cast(unsigned int, f);
  u += 0x7FFFu + ((u >> 16) & 1u);
  return (ushort_t)(u >> 16);
}
__device__ __forceinline__ ushort_t f2h_bits(float f) {
  _Float16 h = (_Float16)f;
  return __builtin_bit_cast(ushort_t, h);
}
__device__ __forceinline__ float h2f(ushort_t u) {
  return (float)__builtin_bit_cast(_Float16, u);
}
__device__ __forceinline__ half8 cvt_bf8_h8(ushort8 u) {
  half8 r;
#pragma unroll
  for (int i = 0; i < 8; ++i) r[i] = (_Float16)bf2f(u[i]);
  return r;
}
__device__ __forceinline__ float ldv(const void* p, long i, int isf32) {
  return isf32 ? ((const float*)p)[i] : bf2f(((const ushort_t*)p)[i]);
}
__device__ __forceinline__ half8 ld8h(const void* p, long i, int isf32) {
  half8 r;
  if (isf32) {
    const float* f = (const float*)p + i;
#pragma unroll
    for (int k = 0; k < 8; ++k) r[k] = (_Float16)f[k];
  } else {
    ushort8 u = *(const ushort8*)((const ushort_t*)p + i);
    r = cvt_bf8_h8(u);
  }
  return r;
}

// inline dtype detect (wave-parallel, ballot-uniform)
__device__ __forceinline__ int detect_isf32(const void* p, int tid) {
  const ushort_t* u = (const ushort_t*)p;
  float a = fabsf(bf2f(u[2 * (tid & 63)]));
  int ok = (a > 1e-4f && a < 64.f) ? 1 : 0;
  unsigned long long m = __ballot(ok);
  return (__popcll(m) > 32) ? 0 : 1;
}

// ------- kernel 1 (big-ws): mean over T  +  emit xT[b][c][t][j32] f16 -------
__global__ __launch_bounds__(256) void k_meanT(const void* __restrict__ x,
                                               float* __restrict__ xt,
                                               ushort_t* __restrict__ xT) {
  const int bc = blockIdx.x;  // b*128 + c
  const int b = bc >> 7, c = bc & 127;
  const long base = (long)bc * 3200;
  const int tid = threadIdx.x;
  const int isf32 = detect_isf32((const ushort_t*)x + base, tid);
  __shared__ float pl[3200];
  __shared__ float red[8][32];
  if (isf32) {
    const f32x4* src = (const f32x4*)((const float*)x + base);
    for (int i = tid; i < 800; i += 256) *(f32x4*)&pl[i * 4] = src[i];
  } else {
    const ushort4_t* src = (const ushort4_t*)((const ushort_t*)x + base);
    for (int i = tid; i < 800; i += 256) {
      ushort4_t u = src[i];
      f32x4 v;
#pragma unroll
      for (int r = 0; r < 4; ++r) v[r] = bf2f(u[r]);
      *(f32x4*)&pl[i * 4] = v;
    }
  }
  __syncthreads();
  // xT write: 512 ushort8 groups, fully coalesced, zero-padded j in [25,32)
  {
    ushort_t* dst = xT + (long)bc * 4096;  // 128 t * 32 j
#pragma unroll
    for (int w = 0; w < 2; ++w) {
      int g = tid + w * 256;          // ushort8 index
      int t = g >> 2, jb = (g & 3) * 8;
      ushort8 u;
#pragma unroll
      for (int r = 0; r < 8; ++r) {
        int j = jb + r;
        u[r] = (j < J_) ? f2h_bits(pl[t * 25 + j]) : (ushort_t)0;
      }
      *(ushort8*)&dst[(long)g * 8] = u;
    }
  }
  // mean reduce
  const int j = tid & 31, g = tid >> 5;
  float s = 0.f;
  if (j < J_) {
#pragma unroll
    for (int i = 0; i < 16; ++i) s += pl[(g * 16 + i) * 25 + j];
  }
  red[g][j] = s;
  __syncthreads();
  if (tid < 32) {
    float tot = 0.f;
#pragma unroll
    for (int gg = 0; gg < 8; ++gg) tot += red[gg][tid];
    if (tid < J_) xt[b * 4096 + tid * 128 + c] = tot * (1.0f / 128.0f);
  }
}

// ------- kernel 1 (fallback): mean only -------
__global__ __launch_bounds__(256) void k_mean(const void* __restrict__ x,
                                              float* __restrict__ xt) {
  const int bc = blockIdx.x;
  const int b = bc >> 7, c = bc & 127;
  const long base = (long)bc * 3200;
  const int tid = threadIdx.x;
  const int isf32 = detect_isf32((const ushort_t*)x + base, tid);
  __shared__ float pl[3200];
  __shared__ float red[8][32];
  if (isf32) {
    const f32x4* src = (const f32x4*)((const float*)x + base);
    for (int i = tid; i < 800; i += 256) *(f32x4*)&pl[i * 4] = src[i];
  } else {
    const ushort4_t* src = (const ushort4_t*)((const ushort_t*)x + base);
    for (int i = tid; i < 800; i += 256) {
      ushort4_t u = src[i];
      f32x4 v;
#pragma unroll
      for (int r = 0; r < 4; ++r) v[r] = bf2f(u[r]);
      *(f32x4*)&pl[i * 4] = v;
    }
  }
  __syncthreads();
  const int j = tid & 31, g = tid >> 5;
  float s = 0.f;
  if (j < J_) {
#pragma unroll
    for (int i = 0; i < 16; ++i) s += pl[(g * 16 + i) * 25 + j];
  }
  red[g][j] = s;
  __syncthreads();
  if (tid < 32) {
    float tot = 0.f;
#pragma unroll
    for (int gg = 0; gg < 8; ++gg) tot += red[gg][tid];
    if (tid < J_) xt[b * 4096 + tid * 128 + c] = tot * (1.0f / 128.0f);
  }
}

// ---------------- kernel 2: per-batch attention -> F[b] (f16), s[b] ---------
__global__ __launch_bounds__(256) void k_attn(
    const float* __restrict__ xt, const void* __restrict__ adj,
    const void* __restrict__ Wk, const void* __restrict__ bk,
    const void* __restrict__ Wq, const void* __restrict__ bq,
    const void* __restrict__ alphap, ushort_t* __restrict__ fkws,
    float* __restrict__ sws) {
  const int b = blockIdx.x;
  const int tid = threadIdx.x;
  const int isf32 = detect_isf32(Wk, tid);
  const int wv = tid >> 6, lane = tid & 63, lrow = lane & 15, quad = lane >> 4;
  const float alpha = ldv(alphap, 0, isf32);

  __shared__ __align__(16) ushort_t xtT[32 * PIT];
  __shared__ __align__(16) ushort_t kkT[32 * PIT];
  __shared__ __align__(16) ushort_t qqT[32 * PIT];
  __shared__ float sc[32 * 33];

  for (int idx = tid; idx < 32 * PIT; idx += 256) {
    int r = idx / PIT, col = idx % PIT;
    float v = (r < J_ && col < 128) ? xt[b * 4096 + r * 128 + col] : 0.f;
    xtT[idx] = f2h_bits(v);
  }
  __syncthreads();

  for (int mat = 0; mat < 2; ++mat) {
    const void* W = mat ? Wq : Wk;
    const void* bias = mat ? bq : bk;
    ushort_t* dstT = mat ? qqT : kkT;
    f32x4 acc[2][2] = {};
    for (int ks = 0; ks < 4; ++ks) {
      half8 bfr[2];
#pragma unroll
      for (int jt = 0; jt < 2; ++jt)
        bfr[jt] = *(const half8*)&xtT[(jt * 16 + lrow) * PIT + ks * 32 + quad * 8];
#pragma unroll
      for (int ot = 0; ot < 2; ++ot) {
        int o = (2 * wv + ot) * 16 + lrow;
        half8 afr = ld8h(W, o * 128 + ks * 32 + quad * 8, isf32);
#pragma unroll
        for (int jt = 0; jt < 2; ++jt)
          acc[ot][jt] = __builtin_amdgcn_mfma_f32_16x16x32_f16(afr, bfr[jt],
                                                               acc[ot][jt], 0, 0, 0);
      }
    }
#pragma unroll
    for (int ot = 0; ot < 2; ++ot) {
      int obase = (2 * wv + ot) * 16 + quad * 4;
#pragma unroll
      for (int jt = 0; jt < 2; ++jt) {
        int j = jt * 16 + lrow;
        ushort_t pack[4];
#pragma unroll
        for (int r = 0; r < 4; ++r)
          pack[r] = f2h_bits(acc[ot][jt][r] + ldv(bias, obase + r, isf32));
        *(ushort4_t*)&dstT[j * PIT + obase] = *(ushort4_t*)pack;
      }
    }
  }
  __syncthreads();

  {
    const int mt = wv >> 1, nt = wv & 1;
    f32x4 acc = {};
    for (int ks = 0; ks < 4; ++ks) {
      half8 afr = *(const half8*)&qqT[(mt * 16 + lrow) * PIT + ks * 32 + quad * 8];
      half8 bfr = *(const half8*)&kkT[(nt * 16 + lrow) * PIT + ks * 32 + quad * 8];
      acc = __builtin_amdgcn_mfma_f32_16x16x32_f16(afr, bfr, acc, 0, 0, 0);
    }
    const float rs = 0.08838834764831845f;
#pragma unroll
    for (int r = 0; r < 4; ++r)
      sc[(mt * 16 + quad * 4 + r) * 33 + nt * 16 + lrow] = acc[r] * rs;
  }
  __syncthreads();

  if (tid < J_) {
    float m = -1e30f;
    for (int k = 0; k < J_; ++k) m = fmaxf(m, sc[tid * 33 + k]);
    float sum = 0.f;
    for (int k = 0; k < J_; ++k) {
      float e = expf(sc[tid * 33 + k] - m);
      sc[tid * 33 + k] = e;
      sum += e;
    }
    float inv = 1.f / sum;
    for (int k = 0; k < J_; ++k) sc[tid * 33 + k] *= inv;
  }
  __syncthreads();

  for (int idx = tid; idx < 1280; idx += 256) {
    int k = idx / XP, jj = idx % XP;
    float v = 0.f;
    if (k < J_ && jj < J_) {
      v = ldv(adj, jj * J_ + k, isf32);
      float d = 0.f;
      for (int m = 0; m < J_; ++m) d += ldv(adj, jj * J_ + m, isf32) * sc[m * 33 + k];
      v += alpha * d;
    }
    fkws[b * 1280 + idx] = f2h_bits(v);
  }
  if (tid < 32) {
    float v = 0.f;
    if (tid < J_) {
      float d = 0.f;
      for (int jj = 0; jj < J_; ++jj) d += sc[jj * 33 + tid];
      v = 1.f + alpha * d;
    }
    sws[b * 32 + tid] = v;
  }
}

// ======= kernel 3 (big-ws): reads xT f16, fully streaming ===================
#define SM_FK 0
#define SM_GT 2560
#define SM_TOT 33024
__global__ __launch_bounds__(256, 4) void k_mainT(
    const ushort_t* __restrict__ xT, const void* __restrict__ Ws,
    const void* __restrict__ bs, const void* __restrict__ gamma,
    const void* __restrict__ beta, const void* __restrict__ rmean,
    const void* __restrict__ rvar, const ushort_t* __restrict__ fkws,
    const float* __restrict__ sws, void* __restrict__ out) {
  const int tid = threadIdx.x;
  const int isf32 = detect_isf32(Ws, tid);
  const int b = blockIdx.x >> 5, tb = blockIdx.x & 31, t0 = tb * TT;
  const int wv = tid >> 6, lane = tid & 63, lrow = lane & 15, quad = lane >> 4;

  __shared__ __align__(16) char smem[SM_TOT];
  __shared__ float bnscale[128], bnshift[128], bsv[128], sv[32];
  ushort_t* fk = (ushort_t*)(smem + SM_FK);
  ushort_t* gt = (ushort_t*)(smem + SM_GT);
  ushort_t* outbuf = (ushort_t*)(smem + SM_GT);

  half8 wsf[2][4];
#pragma unroll
  for (int ot = 0; ot < 2; ++ot) {
    int o = (2 * wv + ot) * 16 + lrow;
#pragma unroll
    for (int ks = 0; ks < 4; ++ks)
      wsf[ot][ks] = ld8h(Ws, o * 128 + ks * 32 + quad * 8, isf32);
  }

  for (int i = tid; i < 160; i += 256)
    *(ushort8*)&fk[i * 8] = *(const ushort8*)&fkws[b * 1280 + i * 8];
  for (int i = tid; i < 204; i += 256) {
    int row = 100 + i / 17, col8 = (i % 17) * 8;
    ushort8 z = {};
    *(ushort8*)&gt[row * GP + col8] = z;
  }
  if (tid < 32) sv[tid] = sws[b * 32 + tid];
  if (tid < 128) {
    float g = ldv(gamma, tid, isf32), v = ldv(rvar, tid, isf32);
    float scl = g * rsqrtf(v + 1e-5f);
    bnscale[tid] = scl;
    bnshift[tid] = ldv(beta, tid, isf32) - ldv(rmean, tid, isf32) * scl;
    bsv[tid] = ldv(bs, tid, isf32);
  }
  __syncthreads();

  // stage A: G^T[(t,k)][c] = sum_j F^T[k][j]*xT[c][t][j]; xT pads are zero.
  {
    half8 afr[2];
#pragma unroll
    for (int mt = 0; mt < 2; ++mt)
      afr[mt] = *(const half8*)&fk[(mt * 16 + lrow) * XP + quad * 8];
#pragma unroll
    for (int t = 0; t < TT; ++t) {
#pragma unroll
      for (int ci = 0; ci < 2; ++ci) {
        int ct = 2 * wv + ci;
        long p = ((long)(b * 128 + ct * 16 + lrow) * 128 + (t0 + t)) * 32 + quad * 8;
        half8 bfr = __builtin_bit_cast(half8, *(const ushort8*)&xT[p]);
        f32x4 accg[2] = {};
#pragma unroll
        for (int mt = 0; mt < 2; ++mt)
          accg[mt] = __builtin_amdgcn_mfma_f32_16x16x32_f16(afr[mt], bfr, accg[mt], 0, 0, 0);
#pragma unroll
        for (int mt = 0; mt < 2; ++mt)
#pragma unroll
          for (int r = 0; r < 4; ++r) {
            int kk = mt * 16 + quad * 4 + r;
            if (kk < J_)
              gt[(t * 25 + kk) * GP + ct * 16 + lrow] = f2h_bits(accg[mt][r]);
          }
      }
    }
  }
  __syncthreads();

  // stage B
  f32x4 acc[2][7];
#pragma unroll
  for (int ot = 0; ot < 2; ++ot)
#pragma unroll
    for (int nt = 0; nt < 7; ++nt) acc[ot][nt] = (f32x4){};
  for (int ks = 0; ks < 4; ++ks) {
#pragma unroll
    for (int nt = 0; nt < 7; ++nt) {
      half8 bfr = *(const half8*)&gt[(nt * 16 + lrow) * GP + ks * 32 + quad * 8];
#pragma unroll
      for (int ot = 0; ot < 2; ++ot)
        acc[ot][nt] = __builtin_amdgcn_mfma_f32_16x16x32_f16(wsf[ot][ks], bfr,
                                                             acc[ot][nt], 0, 0, 0);
    }
  }
  __syncthreads();

#pragma unroll
  for (int nt = 0; nt < 7; ++nt) {
    int n = nt * 16 + lrow;
    if (n < 100) {
      float svk = sv[n % 25];
#pragma unroll
      for (int ot = 0; ot < 2; ++ot) {
        int obase = (2 * wv + ot) * 16 + quad * 4;
#pragma unroll
        for (int r = 0; r < 4; ++r) {
          int o = obase + r;
          float v = acc[ot][nt][r] + bsv[o] * svk;
          v = v * bnscale[o] + bnshift[o];
          outbuf[o * 100 + n] = f2h_bits(fmaxf(v, 0.f));
        }
      }
    }
  }
  __syncthreads();

  {
    const long obase = ((long)(b * 128) * 128 + t0) * 25;
    if (isf32) {
      float* of = (float*)out + obase;
      for (int idx = tid; idx < 3200; idx += 256) {
        int o = idx / 25, q = idx % 25;
        ushort4_t u = *(const ushort4_t*)&outbuf[o * 100 + q * 4];
        f32x4 v;
#pragma unroll
        for (int r = 0; r < 4; ++r) v[r] = h2f(u[r]);
        *(f32x4*)(of + (long)o * 3200 + q * 4) = v;
      }
    } else {
      ushort_t* oh = (ushort_t*)out + obase;
      for (int idx = tid; idx < 3200; idx += 256) {
        int o = idx / 25, q = idx % 25;
        ushort4_t u = *(const ushort4_t*)&outbuf[o * 100 + q * 4];
        ushort4_t w;
#pragma unroll
        for (int r = 0; r < 4; ++r) w[r] = f2bf(h2f(u[r]));
        *(ushort4_t*)(oh + (long)o * 3200 + q * 4) = w;
      }
    }
  }
}

// ======= kernel 3 (fallback): round-4 version, reads x directly =============
__global__ __launch_bounds__(256, 4) void k_main(
    const void* __restrict__ x, const void* __restrict__ Ws,
    const void* __restrict__ bs, const void* __restrict__ gamma,
    const void* __restrict__ beta, const void* __restrict__ rmean,
    const void* __restrict__ rvar, const ushort_t* __restrict__ fkws,
    const float* __restrict__ sws, void* __restrict__ out) {
  const int tid = threadIdx.x;
  const int isf32 = detect_isf32(Ws, tid);
  const int b = blockIdx.x >> 5, tb = blockIdx.x & 31, t0 = tb * TT;
  const int wv = tid >> 6, lane = tid & 63, lrow = lane & 15, quad = lane >> 4;

  __shared__ __align__(16) char smem[SM_TOT];
  __shared__ float bnscale[128], bnshift[128], bsv[128], sv[32];
  ushort_t* fk = (ushort_t*)(smem + SM_FK);
  ushort_t* gt = (ushort_t*)(smem + SM_GT);
  ushort_t* outbuf = (ushort_t*)(smem + SM_GT);

  half8 wsf[2][4];
#pragma unroll
  for (int ot = 0; ot < 2; ++ot) {
    int o = (2 * wv + ot) * 16 + lrow;
#pragma unroll
    for (int ks = 0; ks < 4; ++ks)
      wsf[ot][ks] = ld8h(Ws, o * 128 + ks * 32 + quad * 8, isf32);
  }

  for (int i = tid; i < 160; i += 256)
    *(ushort8*)&fk[i * 8] = *(const ushort8*)&fkws[b * 1280 + i * 8];
  for (int i = tid; i < 204; i += 256) {
    int row = 100 + i / 17, col8 = (i % 17) * 8;
    ushort8 z = {};
    *(ushort8*)&gt[row * GP + col8] = z;
  }
  if (tid < 32) sv[tid] = sws[b * 32 + tid];
  if (tid < 128) {
    float g = ldv(gamma, tid, isf32), v = ldv(rvar, tid, isf32);
    float scl = g * rsqrtf(v + 1e-5f);
    bnscale[tid] = scl;
    bnshift[tid] = ldv(beta, tid, isf32) - ldv(rmean, tid, isf32) * scl;
    bsv[tid] = ldv(bs, tid, isf32);
  }
  __syncthreads();

  {
    half8 afr[2];
#pragma unroll
    for (int mt = 0; mt < 2; ++mt)
      afr[mt] = *(const half8*)&fk[(mt * 16 + lrow) * XP + quad * 8];
    const float* xf = (const float*)x;
    const ushort_t* xh = (const ushort_t*)x;
#pragma unroll
    for (int t = 0; t < TT; ++t) {
#pragma unroll
      for (int ci = 0; ci < 2; ++ci) {
        int ct = 2 * wv + ci;
        long p = (long)b * 409600 + (long)(ct * 16 + lrow) * 3200 + (t0 + t) * 25;
        half8 bfr;
        if (quad < 3) {
          if (isf32) {
            f32x4u v0 = *(const f32x4u*)(xf + p + quad * 8);
            f32x4u v1 = *(const f32x4u*)(xf + p + quad * 8 + 4);
#pragma unroll
            for (int r = 0; r < 4; ++r) {
              bfr[r] = (_Float16)v0[r];
              bfr[4 + r] = (_Float16)v1[r];
            }
          } else {
            ushort8u u = *(const ushort8u*)(xh + p + quad * 8);
#pragma unroll
            for (int r = 0; r < 8; ++r) bfr[r] = (_Float16)bf2f(u[r]);
          }
        } else {
          bfr = (half8){};
          bfr[0] = (_Float16)(isf32 ? xf[p + 24] : bf2f(xh[p + 24]));
        }
        f32x4 accg[2] = {};
#pragma unroll
        for (int mt = 0; mt < 2; ++mt)
          accg[mt] = __builtin_amdgcn_mfma_f32_16x16x32_f16(afr[mt], bfr, accg[mt], 0, 0, 0);
#pragma unroll
        for (int mt = 0; mt < 2; ++mt)
#pragma unroll
          for (int r = 0; r < 4; ++r) {
            int kk = mt * 16 + quad * 4 + r;
            if (kk < J_)
              gt[(t * 25 + kk) * GP + ct * 16 + lrow] = f2h_bits(accg[mt][r]);
          }
      }
    }
  }
  __syncthreads();

  f32x4 acc[2][7];
#pragma unroll
  for (int ot = 0; ot < 2; ++ot)
#pragma unroll
    for (int nt = 0; nt < 7; ++nt) acc[ot][nt] = (f32x4){};
  for (int ks = 0; ks < 4; ++ks) {
#pragma unroll
    for (int nt = 0; nt < 7; ++nt) {
      half8 bfr = *(const half8*)&gt[(nt * 16 + lrow) * GP + ks * 32 + quad * 8];
#pragma unroll
      for (int ot = 0; ot < 2; ++ot)
        acc[ot][nt] = __builtin_amdgcn_mfma_f32_16x16x32_f16(wsf[ot][ks], bfr,
                                                             acc[ot][nt], 0, 0, 0);
    }
  }
  __syncthreads();

#pragma unroll
  for (int nt = 0; nt < 7; ++nt) {
    int n = nt * 16 + lrow;
    if (n < 100) {
      float svk = sv[n % 25];
#pragma unroll
      for (int ot = 0; ot < 2; ++ot) {
        int obase = (2 * wv + ot) * 16 + quad * 4;
#pragma unroll
        for (int r = 0; r < 4; ++r) {
          int o = obase + r;
          float v = acc[ot][nt][r] + bsv[o] * svk;
          v = v * bnscale[o] + bnshift[o];
          outbuf[o * 100 + n] = f2h_bits(fmaxf(v, 0.f));
        }
      }
    }
  }
  __syncthreads();

  {
    const long obase = ((long)(b * 128) * 128 + t0) * 25;
    if (isf32) {
      float* of = (float*)out + obase;
      for (int idx = tid; idx < 3200; idx += 256) {
        int o = idx / 25, q = idx % 25;
        ushort4_t u = *(const ushort4_t*)&outbuf[o * 100 + q * 4];
        f32x4 v;
#pragma unroll
        for (int r = 0; r < 4; ++r) v[r] = h2f(u[r]);
        *(f32x4*)(of + (long)o * 3200 + q * 4) = v;
      }
    } else {
      ushort_t* oh = (ushort_t*)out + obase;
      for (int idx = tid; idx < 3200; idx += 256) {
        int o = idx / 25, q = idx % 25;
        ushort4_t u = *(const ushort4_t*)&outbuf[o * 100 + q * 4];
        ushort4_t w;
#pragma unroll
        for (int r = 0; r < 4; ++r) w[r] = f2bf(h2f(u[r]));
        *(ushort4_t*)(oh + (long)o * 3200 + q * 4) = w;
      }
    }
  }
}

extern "C" void kernel_launch(void* const* d_in, const int* in_sizes, int n_in,
                              void* d_out, int out_size, void* d_ws, size_t ws_size,
                              hipStream_t stream) {
  const void* x = d_in[0];
  const void* adj = d_in[1];
  const void* Wk = d_in[2];
  const void* bk = d_in[3];
  const void* Wq = d_in[4];
  const void* bq = d_in[5];
  const void* Ws = d_in[6];
  const void* bsp = d_in[7];
  const void* gamma = d_in[8];
  const void* beta = d_in[9];
  const void* rmean = d_in[10];
  const void* rvar = d_in[11];
  const void* alphap = d_in[12];

  char* ws = (char*)d_ws;
  float* xt = (float*)ws;                                   // 1 MiB
  ushort_t* fkws = (ushort_t*)(ws + 64 * 4096 * 4);         // 160 KiB
  float* sws = (float*)(ws + 64 * 4096 * 4 + 64 * 1280 * 2);
  ushort_t* xT = (ushort_t*)(ws + 2 * 1024 * 1024);         // 64 MiB (big-ws)

  const size_t need = 2ull * 1024 * 1024 + 64ull * 1024 * 1024;
  const bool bigws = ws_size >= need;

  if (bigws) {
    k_meanT<<<B_ * C_, 256, 0, stream>>>(x, xt, xT);
    k_attn<<<B_, 256, 0, stream>>>(xt, adj, Wk, bk, Wq, bq, alphap, fkws, sws);
    k_mainT<<<B_ * (T_ / TT), 256, 0, stream>>>(xT, Ws, bsp, gamma, beta, rmean,
                                                rvar, fkws, sws, d_out);
  } else {
    k_mean<<<B_ * C_, 256, 0, stream>>>(x, xt);
    k_attn<<<B_, 256, 0, stream>>>(xt, adj, Wk, bk, Wq, bq, alphap, fkws, sws);
    k_main<<<B_ * (T_ / TT), 256, 0, stream>>>(x, Ws, bsp, gamma, beta, rmean,
                                               rvar, fkws, sws, d_out);
  }
}